// Round 1
// baseline (588.949 us; speedup 1.0000x reference)
//
#include <hip/hip_runtime.h>

#define BATCH 32
#define SEQL 4096
#define DIM 768
#define D4 192           // DIM / 4
#define WIN 32
#define NPOS 65          // 2*WIN + 1
#define CHUNKS 13
#define PERCHUNK 5       // CHUNKS * PERCHUNK == NPOS
#define LN_EPS 1e-5f

// Kernel A: partial window sums of (alt - ref).
// grid = (CHUNKS, BATCH), block = 192 threads (one float4 of D per thread).
__global__ __launch_bounds__(D4) void pool_partial_kernel(
    const float4* __restrict__ refv, const float4* __restrict__ altv,
    const int* __restrict__ pos, float4* __restrict__ wsv) {
  const int b = blockIdx.y;
  const int chunk = blockIdx.x;
  const int tid = threadIdx.x;
  const int p0 = pos[b] - WIN + chunk * PERCHUNK;

  float4 acc = make_float4(0.f, 0.f, 0.f, 0.f);
#pragma unroll
  for (int i = 0; i < PERCHUNK; ++i) {
    const int p = p0 + i;
    if (p >= 0 && p < SEQL) {
      const size_t off = ((size_t)b * SEQL + p) * D4 + tid;
      const float4 a = altv[off];
      const float4 r = refv[off];
      acc.x += a.x - r.x;
      acc.y += a.y - r.y;
      acc.z += a.z - r.z;
      acc.w += a.w - r.w;
    }
  }
  wsv[((size_t)b * CHUNKS + chunk) * D4 + tid] = acc;
}

// Kernel B: reduce partials -> masked mean -> LayerNorm over D.
// grid = BATCH, block = 192 threads (3 waves).
__global__ __launch_bounds__(D4) void ln_kernel(
    const float4* __restrict__ wsv, const int* __restrict__ pos,
    const float4* __restrict__ gammav, const float4* __restrict__ betav,
    float4* __restrict__ outv) {
  const int b = blockIdx.x;
  const int tid = threadIdx.x;

  const int p = pos[b];
  const int lo = (p - WIN) > 0 ? (p - WIN) : 0;
  const int hi = (p + WIN) < (SEQL - 1) ? (p + WIN) : (SEQL - 1);
  const float inv_cnt = 1.f / (float)(hi - lo + 1);

  float4 s = make_float4(0.f, 0.f, 0.f, 0.f);
#pragma unroll
  for (int c = 0; c < CHUNKS; ++c) {
    const float4 v = wsv[((size_t)b * CHUNKS + c) * D4 + tid];
    s.x += v.x; s.y += v.y; s.z += v.z; s.w += v.w;
  }
  s.x *= inv_cnt; s.y *= inv_cnt; s.z *= inv_cnt; s.w *= inv_cnt;

  float lsum = s.x + s.y + s.z + s.w;
  float lsq  = s.x * s.x + s.y * s.y + s.z * s.z + s.w * s.w;

  // wave(64)-level butterfly reduce
#pragma unroll
  for (int off = 32; off > 0; off >>= 1) {
    lsum += __shfl_down(lsum, off);
    lsq  += __shfl_down(lsq, off);
  }

  __shared__ float sh[6];
  const int wave = tid >> 6;
  if ((tid & 63) == 0) {
    sh[wave] = lsum;
    sh[3 + wave] = lsq;
  }
  __syncthreads();

  const float tot   = sh[0] + sh[1] + sh[2];
  const float totsq = sh[3] + sh[4] + sh[5];
  const float mu  = tot * (1.f / (float)DIM);
  const float var = totsq * (1.f / (float)DIM) - mu * mu;
  const float rstd = rsqrtf(var + LN_EPS);

  const float4 g  = gammav[tid];
  const float4 bb = betav[tid];
  float4 o;
  o.x = (s.x - mu) * rstd * g.x + bb.x;
  o.y = (s.y - mu) * rstd * g.y + bb.y;
  o.z = (s.z - mu) * rstd * g.z + bb.z;
  o.w = (s.w - mu) * rstd * g.w + bb.w;
  outv[(size_t)b * D4 + tid] = o;
}

extern "C" void kernel_launch(void* const* d_in, const int* in_sizes, int n_in,
                              void* d_out, int out_size, void* d_ws, size_t ws_size,
                              hipStream_t stream) {
  const float* ref_repr = (const float*)d_in[0];
  const float* alt_repr = (const float*)d_in[1];
  const int*   vpos     = (const int*)d_in[2];
  const float* gamma    = (const float*)d_in[3];
  const float* beta     = (const float*)d_in[4];
  float* out = (float*)d_out;
  float* ws  = (float*)d_ws;   // needs 32*13*768 floats = 1.27 MB

  dim3 gridA(CHUNKS, BATCH);
  pool_partial_kernel<<<gridA, D4, 0, stream>>>(
      (const float4*)ref_repr, (const float4*)alt_repr, vpos, (float4*)ws);

  ln_kernel<<<BATCH, D4, 0, stream>>>(
      (const float4*)ws, vpos, (const float4*)gamma, (const float4*)beta,
      (float4*)out);
}